// Round 8
// baseline (273.928 us; speedup 1.0000x reference)
//
#include <hip/hip_runtime.h>
#include <stdint.h>
#include <math.h>

#define NB 64      // batch
#define BT 512     // time steps
#define NH 768     // hidden
#define NL 9       // labels
#define PADW 772   // padded W row stride (floats)
#define CBB 4      // batches per crf block (16 blocks x 4 = 64 exact)
#define BPROW 16   // bp_lds row stride in bytes

__device__ __forceinline__ float rlane(float v, int i) {
    return __int_as_float(__builtin_amdgcn_readlane(__float_as_int(v), i));
}
__device__ __forceinline__ float bperm(int addr, float v) {
    return __int_as_float(__builtin_amdgcn_ds_bpermute(addr, __float_as_int(v)));
}

// DPP-based cross-lane add (gemm reduction): VALU, not DS pipe.
template<int CTRL, int RM>
__device__ __forceinline__ float dppadd(float v) {
    const int t = __builtin_amdgcn_update_dpp(0, __float_as_int(v), CTRL, RM, 0xf, true);
    return v + __int_as_float(t);
}
__device__ __forceinline__ float wave_sum_dpp(float v) {
    v = dppadd<0x111, 0xf>(v);
    v = dppadd<0x112, 0xf>(v);
    v = dppadd<0x114, 0xf>(v);
    v = dppadd<0x118, 0xf>(v);
    v = dppadd<0x142, 0xa>(v);
    v = dppadd<0x143, 0xc>(v);
    return rlane(v, 63);
}

// ---------------------------------------------------------------------------
// Kernel 1: logits = x @ W + b.  (Round-0 verbatim — best verified config.)
// ---------------------------------------------------------------------------
__global__ __launch_bounds__(256, 2) void gemm_kernel(
    const float* __restrict__ x, const float* __restrict__ W,
    const float* __restrict__ bias, float* __restrict__ logits)
{
    __shared__ float wT[NL * PADW];

    const int tid  = threadIdx.x;
    const int lane = tid & 63;

    for (int i = tid; i < NH * NL; i += 256) {
        const int h = i / NL, l = i - h * NL;
        wT[l * PADW + h] = W[i];
    }
    __syncthreads();

    float wr[3][NL][4];
#pragma unroll
    for (int k = 0; k < 3; ++k)
#pragma unroll
        for (int l = 0; l < NL; ++l) {
            const float4 w4 = *(const float4*)&wT[l * PADW + k * 256 + lane * 4];
            wr[k][l][0] = w4.x; wr[k][l][1] = w4.y;
            wr[k][l][2] = w4.z; wr[k][l][3] = w4.w;
        }
    const float bj = bias[lane < NL ? lane : 0];

    const int gwave = (blockIdx.x * blockDim.x + tid) >> 6;
    const int nw    = (gridDim.x * blockDim.x) >> 6;
    const int nrows = NB * BT;
    int row = gwave;
    if (row >= nrows) return;

    const float4* xr = (const float4*)(x + (size_t)row * NH);
    float4 a0 = xr[lane], a1 = xr[64 + lane], a2 = xr[128 + lane];

    while (true) {
        const int nrow = row + nw;
        float4 b0, b1, b2;
        if (nrow < nrows) {
            const float4* xn = (const float4*)(x + (size_t)nrow * NH);
            b0 = xn[lane]; b1 = xn[64 + lane]; b2 = xn[128 + lane];
        }

        float acc[NL];
#pragma unroll
        for (int l = 0; l < NL; ++l) {
            float s = a0.x * wr[0][l][0];
            s = fmaf(a0.y, wr[0][l][1], s);
            s = fmaf(a0.z, wr[0][l][2], s);
            s = fmaf(a0.w, wr[0][l][3], s);
            s = fmaf(a1.x, wr[1][l][0], s);
            s = fmaf(a1.y, wr[1][l][1], s);
            s = fmaf(a1.z, wr[1][l][2], s);
            s = fmaf(a1.w, wr[1][l][3], s);
            s = fmaf(a2.x, wr[2][l][0], s);
            s = fmaf(a2.y, wr[2][l][1], s);
            s = fmaf(a2.z, wr[2][l][2], s);
            s = fmaf(a2.w, wr[2][l][3], s);
            acc[l] = s;
        }
        float sum[NL];
#pragma unroll
        for (int l = 0; l < NL; ++l) sum[l] = wave_sum_dpp(acc[l]);
        float outv = sum[0];
#pragma unroll
        for (int l = 1; l < NL; ++l) outv = (lane == l) ? sum[l] : outv;
        if (lane < NL) logits[(size_t)row * NL + lane] = outv + bj;

        row = nrow;
        if (row >= nrows) break;
        a0 = b0; a1 = b1; a2 = b2;
    }
}

// ---------------------------------------------------------------------------
// Kernel 2: CRF.  16 blocks x 256 threads, 4 batches/block.
// Scan waves pack 4 batches: lane=(batch-slot bl, label j); the 9-alpha
// gather is ds_bpermute with loop-invariant per-lane addresses -> one
// gather serves 4 batches (was 9 readlanes per single batch).  All values
// and summation orders bit-identical to the verified Round-0 kernel.
// Viterbi computes backpointers in-lane during the scan (all 9 candidates
// are in-lane after the gather) -> no val_lds, no bp-recompute phase.
// Backtrack: Round-0 pipelined serial walk, 4 lanes walk 4 batches at once.
// ---------------------------------------------------------------------------
__global__ __launch_bounds__(256) void crf_kernel(
    const float* __restrict__ logits, const float* __restrict__ trans,
    const int* __restrict__ label, const int* __restrict__ seqlen,
    float* __restrict__ vit_out, float* __restrict__ stats)
{
    __shared__ float    trans_lds[NL * NL];
    __shared__ uint8_t  bp_lds[CBB][(BT - 1) * BPROW];   // 32704 B
    __shared__ uint64_t packed_lds[CBB][BT - 1];         // 16352 B
    __shared__ uint8_t  vit_lds[CBB][BT];                //  2048 B
    __shared__ float    xw[4][4];

    const int tid  = threadIdx.x;
    const int lane = tid & 63;
    const int wv   = tid >> 6;
    const int b0   = blockIdx.x * CBB;

    if (tid < NL * NL) trans_lds[tid] = trans[tid];
    __syncthreads();

    // lane -> (batch-slot, label) for scan waves; lanes 36..63 duplicate (3,8)
    int bl = lane / 9, j = lane - bl * 9;
    if (lane >= 36) { bl = 3; j = 8; }
    const bool act = (lane < 36);
    const int bg   = b0 + bl;
    const int sl   = seqlen[bg];
    const float* lgb = logits + (size_t)bg * BT * NL;
    int adr[9];
#pragma unroll
    for (int i = 0; i < 9; ++i) adr[i] = (bl * 9 + i) * 4;

    if (wv == 0) {
        // ---- logZ scan, scaled-exp domain (bit-identical to R0) ----
        float E[9];
#pragma unroll
        for (int i = 0; i < 9; ++i) E[i] = __expf(trans_lds[i * NL + j]) * 0.125f;
        float A = __expf(lgb[j]);
        int lc = 0;
        float cur[8], nxt[8];
#pragma unroll
        for (int s = 0; s < 8; ++s) cur[s] = lgb[(1 + s) * NL + j];
        for (int tb = 1; tb < BT + 8; tb += 8) {
#pragma unroll
            for (int s = 0; s < 8; ++s) {
                int tt = tb + 8 + s; tt = tt > BT - 1 ? BT - 1 : tt;
                nxt[s] = lgb[tt * NL + j];
            }
            float P[8];
#pragma unroll
            for (int s = 0; s < 8; ++s) P[s] = __expf(cur[s]);
#pragma unroll
            for (int s = 0; s < 8; ++s) {
                const int t = tb + s;
                const float g0 = bperm(adr[0], A), g1 = bperm(adr[1], A),
                            g2 = bperm(adr[2], A), g3 = bperm(adr[3], A),
                            g4 = bperm(adr[4], A), g5 = bperm(adr[5], A),
                            g6 = bperm(adr[6], A), g7 = bperm(adr[7], A),
                            g8 = bperm(adr[8], A);
                float p0 = g0 * E[0]; p0 = fmaf(g1, E[1], p0); p0 = fmaf(g2, E[2], p0);
                float p1 = g3 * E[3]; p1 = fmaf(g4, E[4], p1); p1 = fmaf(g5, E[5], p1);
                float p2 = g6 * E[6]; p2 = fmaf(g7, E[7], p2); p2 = fmaf(g8, E[8], p2);
                const float An = ((p0 + p1) + p2) * P[s];
                A = (t < sl) ? An : A;
            }
            // exact pow2 renorm (per-lane; uniform within each 9-lane group)
            {
                const float g0 = bperm(adr[0], A), g1 = bperm(adr[1], A),
                            g2 = bperm(adr[2], A), g3 = bperm(adr[3], A),
                            g4 = bperm(adr[4], A), g5 = bperm(adr[5], A),
                            g6 = bperm(adr[6], A), g7 = bperm(adr[7], A),
                            g8 = bperm(adr[8], A);
                const float m = fmaxf(fmaxf(
                    fmaxf(fmaxf(g0, g1), fmaxf(g2, g3)),
                    fmaxf(fmaxf(g4, g5), fmaxf(g6, g7))), g8);
                const int ex = (int)((__float_as_uint(m) >> 23) & 0xFFu) - 126;
                const float sc = __uint_as_float((uint32_t)(127 - ex) << 23);
                A *= sc;
                lc += ex;
            }
#pragma unroll
            for (int s = 0; s < 8; ++s) cur[s] = nxt[s];
        }
        const float g0 = bperm(adr[0], A), g1 = bperm(adr[1], A),
                    g2 = bperm(adr[2], A), g3 = bperm(adr[3], A),
                    g4 = bperm(adr[4], A), g5 = bperm(adr[5], A),
                    g6 = bperm(adr[6], A), g7 = bperm(adr[7], A),
                    g8 = bperm(adr[8], A);
        const float sum = ((g0 + g1) + (g2 + g3)) + ((g4 + g5) + (g6 + g7)) + g8;
        const float logZ = logf(sum) +
            ((float)lc + 3.0f * (float)(sl - 1)) * 0.6931471805599453f;
        if (act && j == 0) stats[bg * 8 + 1] = logZ;
    } else if (wv == 1) {
        // ---- viterbi scan + in-lane backpointers (bit-exact first-max) ----
        float tc[9];
#pragma unroll
        for (int i = 0; i < 9; ++i) tc[i] = trans_lds[i * NL + j];
        float v = lgb[j];
        float cur[8], nxt[8];
#pragma unroll
        for (int s = 0; s < 8; ++s) cur[s] = lgb[(1 + s) * NL + j];
        for (int tb = 1; tb < BT + 8; tb += 8) {
#pragma unroll
            for (int s = 0; s < 8; ++s) {
                int tt = tb + 8 + s; tt = tt > BT - 1 ? BT - 1 : tt;
                nxt[s] = lgb[tt * NL + j];
            }
#pragma unroll
            for (int s = 0; s < 8; ++s) {
                const int t = tb + s;
                const float g0 = bperm(adr[0], v), g1 = bperm(adr[1], v),
                            g2 = bperm(adr[2], v), g3 = bperm(adr[3], v),
                            g4 = bperm(adr[4], v), g5 = bperm(adr[5], v),
                            g6 = bperm(adr[6], v), g7 = bperm(adr[7], v),
                            g8 = bperm(adr[8], v);
                const float c0 = g0 + tc[0], c1 = g1 + tc[1], c2 = g2 + tc[2],
                            c3 = g3 + tc[3], c4 = g4 + tc[4], c5 = g5 + tc[5],
                            c6 = g6 + tc[6], c7 = g7 + tc[7], c8 = g8 + tc[8];
                const float m = fmaxf(fmaxf(fmaxf(fmaxf(c0, c1), c2),
                                            fmaxf(fmaxf(c3, c4), c5)),
                                      fmaxf(fmaxf(c6, c7), c8));
                const float nv = m + cur[s];
                v = (t < sl) ? nv : v;
                int bi = 8;
                bi = (c7 == m) ? 7 : bi;
                bi = (c6 == m) ? 6 : bi;
                bi = (c5 == m) ? 5 : bi;
                bi = (c4 == m) ? 4 : bi;
                bi = (c3 == m) ? 3 : bi;
                bi = (c2 == m) ? 2 : bi;
                bi = (c1 == m) ? 1 : bi;
                bi = (c0 == m) ? 0 : bi;
                bi = (t < sl) ? bi : j;           // identity past seqlen
                if (act && t < BT)
                    bp_lds[bl][(t - 1) * BPROW + j] = (uint8_t)bi;
            }
#pragma unroll
            for (int s = 0; s < 8; ++s) cur[s] = nxt[s];
        }
        // last tag = first-argmax(alphaT)
        const float g0 = bperm(adr[0], v), g1 = bperm(adr[1], v),
                    g2 = bperm(adr[2], v), g3 = bperm(adr[3], v),
                    g4 = bperm(adr[4], v), g5 = bperm(adr[5], v),
                    g6 = bperm(adr[6], v), g7 = bperm(adr[7], v),
                    g8 = bperm(adr[8], v);
        const float m = fmaxf(fmaxf(fmaxf(fmaxf(g0, g1), g2),
                                    fmaxf(fmaxf(g3, g4), g5)),
                              fmaxf(fmaxf(g6, g7), g8));
        const int last = (g0 == m) ? 0 : (g1 == m) ? 1 : (g2 == m) ? 2 :
                         (g3 == m) ? 3 : (g4 == m) ? 4 : (g5 == m) ? 5 :
                         (g6 == m) ? 6 : (g7 == m) ? 7 : 8;
        if (act && j == 0) vit_lds[bl][BT - 1] = (uint8_t)last;
    } else {
        // ---- gold-path score: wv2 -> slots 0,1 ; wv3 -> slots 2,3 ----
        const int s0 = (wv - 2) * 2;
#pragma unroll
        for (int k = 0; k < 2; ++k) {
            const int bb  = s0 + k;
            const int bgs = b0 + bb;
            const int sls = seqlen[bgs];
            const int* lab = label + (size_t)bgs * BT;
            const float* lgs = logits + (size_t)bgs * BT * NL;
            float s = 0.f;
            for (int t = lane; t < BT; t += 64) {
                const int lb = lab[t];
                if (t < sls) {
                    s += lgs[t * NL + lb];
                    if (t >= 1) s += trans_lds[lab[t - 1] * NL + lb];
                }
            }
#pragma unroll
            for (int off = 32; off >= 1; off >>= 1) s += __shfl_xor(s, off, 64);
            if (lane == 0) stats[bgs * 8 + 0] = s;
        }
    }
    __syncthreads();

    // ---- pack bp rows: 9 x 4 bits -> u64 ----
    for (int idx = tid; idx < CBB * (BT - 1); idx += 256) {
        const int bb = idx / (BT - 1);
        const int rr = idx - bb * (BT - 1);
        uint64_t p = 0;
#pragma unroll
        for (int i = 0; i < NL; ++i)
            p |= (uint64_t)bp_lds[bb][rr * BPROW + i] << (4 * i);
        packed_lds[bb][rr] = p;
    }
    __syncthreads();

    // ---- serial backtrack: 4 lanes of wave 0 walk 4 batches concurrently.
    //      Loads are address-independent of the tag chain -> pipelined. ----
    if (wv == 0 && lane < CBB) {
        int tag = vit_lds[lane][BT - 1];
        for (int t = BT - 2; t >= 0; --t) {
            const uint64_t row = packed_lds[lane][t];
            tag = (int)((row >> (4 * tag)) & 15u);
            vit_lds[lane][t] = (uint8_t)tag;
        }
    }
    __syncthreads();

    // ---- stats + vit output per batch slot ----
    for (int bb = 0; bb < CBB; ++bb) {
        const int b   = b0 + bb;
        const int sls = seqlen[b];
        const int* lab = label + (size_t)b * BT;
        float accv = 0.f, tpv = 0.f, tnv = 0.f, fpv = 0.f;
        for (int t = tid; t < BT; t += 256) {
            const int tg = vit_lds[bb][t];
            const int lb = lab[t];
            const bool msk = t < sls;
            vit_out[(size_t)b * BT + t] = (float)tg;
            if (msk && tg == lb) accv += 1.f;
            if (lb > 0 && tg == lb) tpv += 1.f;
            if (lb > 0 && tg != lb) tnv += 1.f;
            if (msk && lb == 0 && tg > 0) fpv += 1.f;
        }
#pragma unroll
        for (int off = 32; off >= 1; off >>= 1) {
            accv += __shfl_xor(accv, off, 64);
            tpv  += __shfl_xor(tpv,  off, 64);
            tnv  += __shfl_xor(tnv,  off, 64);
            fpv  += __shfl_xor(fpv,  off, 64);
        }
        if (lane == 0) { xw[0][wv] = accv; xw[1][wv] = tpv; xw[2][wv] = tnv; xw[3][wv] = fpv; }
        __syncthreads();
        if (tid == 0) {
            stats[b * 8 + 2] = xw[0][0] + xw[0][1] + xw[0][2] + xw[0][3];
            stats[b * 8 + 3] = xw[1][0] + xw[1][1] + xw[1][2] + xw[1][3];
            stats[b * 8 + 4] = xw[2][0] + xw[2][1] + xw[2][2] + xw[2][3];
            stats[b * 8 + 5] = xw[3][0] + xw[3][1] + xw[3][2] + xw[3][3];
        }
        __syncthreads();
    }
}

// ---------------------------------------------------------------------------
// Kernel 3: reduce the 64 per-batch partials -> tp, tn, fp, loss, accuracy
// ---------------------------------------------------------------------------
__global__ __launch_bounds__(64) void finalize_kernel(
    const float* __restrict__ stats, const int* __restrict__ seqlen,
    float* __restrict__ out)
{
    const int lane = threadIdx.x;
    float score = stats[lane * 8 + 0];
    float logZ  = stats[lane * 8 + 1];
    float accv  = stats[lane * 8 + 2];
    float tpv   = stats[lane * 8 + 3];
    float tnv   = stats[lane * 8 + 4];
    float fpv   = stats[lane * 8 + 5];
    float nll   = logZ - score;
    float slf   = (float)seqlen[lane];
#pragma unroll
    for (int off = 32; off >= 1; off >>= 1) {
        nll  += __shfl_xor(nll,  off, 64);
        accv += __shfl_xor(accv, off, 64);
        tpv  += __shfl_xor(tpv,  off, 64);
        tnv  += __shfl_xor(tnv,  off, 64);
        fpv  += __shfl_xor(fpv,  off, 64);
        slf  += __shfl_xor(slf,  off, 64);
    }
    if (lane == 0) {
        out[NB * BT + 0] = tpv;
        out[NB * BT + 1] = tnv;
        out[NB * BT + 2] = fpv;
        out[NB * BT + 3] = nll / (float)NB;
        out[NB * BT + 4] = accv / slf;
    }
}

extern "C" void kernel_launch(void* const* d_in, const int* in_sizes, int n_in,
                              void* d_out, int out_size, void* d_ws, size_t ws_size,
                              hipStream_t stream)
{
    const float* x      = (const float*)d_in[0];
    const float* W      = (const float*)d_in[1];
    const float* bias   = (const float*)d_in[2];
    const float* trans  = (const float*)d_in[3];
    const int*   label  = (const int*)d_in[4];
    const int*   seqlen = (const int*)d_in[5];

    float* out    = (float*)d_out;
    float* logits = (float*)d_ws;                  // 64*512*9 floats
    float* stats  = logits + (size_t)NB * BT * NL; // 64*8 floats

    gemm_kernel<<<512, 256, 0, stream>>>(x, W, bias, logits);
    crf_kernel<<<NB / CBB, 256, 0, stream>>>(logits, trans, label, seqlen, out, stats);
    finalize_kernel<<<1, 64, 0, stream>>>(stats, seqlen, out);
}

// Round 9
// 220.649 us; speedup vs baseline: 1.2415x; 1.2415x over previous
//
#include <hip/hip_runtime.h>
#include <stdint.h>
#include <math.h>

#define NB 64      // batch
#define BT 512     // time steps
#define NH 768     // hidden
#define NL 9       // labels
#define PBT 528    // padded time rows in crf LDS
#define PADW 772   // padded W row stride (floats)

__device__ __forceinline__ float rlane(float v, int i) {
    return __int_as_float(__builtin_amdgcn_readlane(__float_as_int(v), i));
}

// DPP move: lane j reads lane (j -/+ k) within its row16; out-of-row -> 0.
template<int CTRL>
__device__ __forceinline__ float dmov(float v) {
    return __int_as_float(__builtin_amdgcn_update_dpp(
        0, __float_as_int(v), CTRL, 0xf, 0xf, true));
}

// DPP cross-lane add (gemm reduction)
template<int CTRL, int RM>
__device__ __forceinline__ float dppadd(float v) {
    const int t = __builtin_amdgcn_update_dpp(0, __float_as_int(v), CTRL, RM, 0xf, true);
    return v + __int_as_float(t);
}
__device__ __forceinline__ float wave_sum_dpp(float v) {
    v = dppadd<0x111, 0xf>(v);
    v = dppadd<0x112, 0xf>(v);
    v = dppadd<0x114, 0xf>(v);
    v = dppadd<0x118, 0xf>(v);
    v = dppadd<0x142, 0xa>(v);
    v = dppadd<0x143, 0xc>(v);
    return rlane(v, 63);
}

// ---------------------------------------------------------------------------
// Kernel 1: logits = x @ W + b.  (Round-0 verbatim — best verified config.)
// ---------------------------------------------------------------------------
__global__ __launch_bounds__(256, 2) void gemm_kernel(
    const float* __restrict__ x, const float* __restrict__ W,
    const float* __restrict__ bias, float* __restrict__ logits)
{
    __shared__ float wT[NL * PADW];

    const int tid  = threadIdx.x;
    const int lane = tid & 63;

    for (int i = tid; i < NH * NL; i += 256) {
        const int h = i / NL, l = i - h * NL;
        wT[l * PADW + h] = W[i];
    }
    __syncthreads();

    float wr[3][NL][4];
#pragma unroll
    for (int k = 0; k < 3; ++k)
#pragma unroll
        for (int l = 0; l < NL; ++l) {
            const float4 w4 = *(const float4*)&wT[l * PADW + k * 256 + lane * 4];
            wr[k][l][0] = w4.x; wr[k][l][1] = w4.y;
            wr[k][l][2] = w4.z; wr[k][l][3] = w4.w;
        }
    const float bj = bias[lane < NL ? lane : 0];

    const int gwave = (blockIdx.x * blockDim.x + tid) >> 6;
    const int nw    = (gridDim.x * blockDim.x) >> 6;
    const int nrows = NB * BT;
    int row = gwave;
    if (row >= nrows) return;

    const float4* xr = (const float4*)(x + (size_t)row * NH);
    float4 a0 = xr[lane], a1 = xr[64 + lane], a2 = xr[128 + lane];

    while (true) {
        const int nrow = row + nw;
        float4 b0, b1, b2;
        if (nrow < nrows) {
            const float4* xn = (const float4*)(x + (size_t)nrow * NH);
            b0 = xn[lane]; b1 = xn[64 + lane]; b2 = xn[128 + lane];
        }

        float acc[NL];
#pragma unroll
        for (int l = 0; l < NL; ++l) {
            float s = a0.x * wr[0][l][0];
            s = fmaf(a0.y, wr[0][l][1], s);
            s = fmaf(a0.z, wr[0][l][2], s);
            s = fmaf(a0.w, wr[0][l][3], s);
            s = fmaf(a1.x, wr[1][l][0], s);
            s = fmaf(a1.y, wr[1][l][1], s);
            s = fmaf(a1.z, wr[1][l][2], s);
            s = fmaf(a1.w, wr[1][l][3], s);
            s = fmaf(a2.x, wr[2][l][0], s);
            s = fmaf(a2.y, wr[2][l][1], s);
            s = fmaf(a2.z, wr[2][l][2], s);
            s = fmaf(a2.w, wr[2][l][3], s);
            acc[l] = s;
        }
        float sum[NL];
#pragma unroll
        for (int l = 0; l < NL; ++l) sum[l] = wave_sum_dpp(acc[l]);
        float outv = sum[0];
#pragma unroll
        for (int l = 1; l < NL; ++l) outv = (lane == l) ? sum[l] : outv;
        if (lane < NL) logits[(size_t)row * NL + lane] = outv + bj;

        row = nrow;
        if (row >= nrows) break;
        a0 = b0; a1 = b1; a2 = b2;
    }
}

// ---------------------------------------------------------------------------
// Kernel 2: per-batch CRF.  Block = 256 (4 waves).  R0 structure.
// THIS ROUND: scan gathers moved from v_readlane (SGPR hazard stalls the
// SIMD issue pipe — R7 evidence) to DPP row_shr/row_shl (pure VALU register
// forwarding).  Per-lane coefficients C[k]=E[j-k] etc. precomputed once;
// invalid slots masked by 0 (logZ, A>0) or -1e30 (viterbi max).
// Viterbi values bit-identical to R0 (same addends, max order-free).
// Also: bp-recompute fused with nibble-pack (one barrier, one array fewer);
// serial backtrack unrolled x8 to batch its address-independent LDS loads.
// ---------------------------------------------------------------------------
__global__ __launch_bounds__(256) void crf_kernel(
    const float* __restrict__ logits, const float* __restrict__ trans,
    const int* __restrict__ label, const int* __restrict__ seqlen,
    float* __restrict__ vit_out, float* __restrict__ stats)
{
    __shared__ __align__(16) float lg_lds[PBT * NL];   // padded, zeros past BT
    __shared__ float    val_lds[BT * NL];              // viterbi alpha vectors
    __shared__ float    trans_lds[NL * NL];
    __shared__ uint64_t packed_lds[BT - 1];
    __shared__ uint8_t  vit_lds[BT];
    __shared__ float    xw[4][4];

    const int b    = blockIdx.x;
    const int tid  = threadIdx.x;
    const int lane = tid & 63;
    const int wv   = tid >> 6;
    const int sl   = seqlen[b];
    const float* lg  = logits + (size_t)b * BT * NL;
    const int*   lab = label + (size_t)b * BT;

    // stage logits (float4) + zero padding + transitions
    {
        const float4* src = (const float4*)lg;
        float4* dst = (float4*)lg_lds;
        for (int idx = tid; idx < BT * NL / 4; idx += 256) dst[idx] = src[idx];
        for (int idx = BT * NL + tid; idx < PBT * NL; idx += 256) lg_lds[idx] = 0.f;
        if (tid < NL * NL) trans_lds[tid] = trans[tid];
    }
    __syncthreads();

    const int j = lane < NL ? lane : 0;

    if (wv == 0) {
        // ---- logZ scan, scaled-exp domain, DPP gather ----
        // per-lane slot coefficients (one-time)
        const float Eo = __expf(trans_lds[j * NL + j]) * 0.125f;
        float Cs[8], Ds[8], Ms[8];
#pragma unroll
        for (int k = 1; k <= 8; ++k) {
            Cs[k - 1] = (j >= k)     ? __expf(trans_lds[(j - k) * NL + j]) * 0.125f : 0.f;
            Ds[k - 1] = (j + k <= 8) ? __expf(trans_lds[(j + k) * NL + j]) * 0.125f : 0.f;
            Ms[k - 1] = (j + k <= 8) ? 1.f : 0.f;
        }
        float A = __expf(lg_lds[j]);
        int lc = 0;
        for (int tb = 1; tb < BT + 8; tb += 8) {
            float P[8];
#pragma unroll
            for (int s = 0; s < 8; ++s) P[s] = __expf(lg_lds[(tb + s) * NL + j]);
#pragma unroll
            for (int s = 0; s < 8; ++s) {
                const int t = tb + s;
                const float g1 = dmov<0x111>(A), g2 = dmov<0x112>(A),
                            g3 = dmov<0x113>(A), g4 = dmov<0x114>(A),
                            g5 = dmov<0x115>(A), g6 = dmov<0x116>(A),
                            g7 = dmov<0x117>(A), g8 = dmov<0x118>(A);
                const float h1 = dmov<0x101>(A), h2 = dmov<0x102>(A),
                            h3 = dmov<0x103>(A), h4 = dmov<0x104>(A),
                            h5 = dmov<0x105>(A), h6 = dmov<0x106>(A),
                            h7 = dmov<0x107>(A), h8 = dmov<0x108>(A);
                float s0 = A * Eo;
                s0 = fmaf(g1, Cs[0], s0); s0 = fmaf(g2, Cs[1], s0);
                s0 = fmaf(g3, Cs[2], s0); s0 = fmaf(g4, Cs[3], s0);
                float s1 = g5 * Cs[4];
                s1 = fmaf(g6, Cs[5], s1); s1 = fmaf(g7, Cs[6], s1);
                s1 = fmaf(g8, Cs[7], s1);
                float s2 = h1 * Ds[0];
                s2 = fmaf(h2, Ds[1], s2); s2 = fmaf(h3, Ds[2], s2);
                s2 = fmaf(h4, Ds[3], s2);
                float s3 = h5 * Ds[4];
                s3 = fmaf(h6, Ds[5], s3); s3 = fmaf(h7, Ds[6], s3);
                s3 = fmaf(h8, Ds[7], s3);
                const float An = ((s0 + s1) + (s2 + s3)) * P[s];
                A = (t < sl) ? An : A;
            }
            // exact pow2 renorm: m = true max of the 9 alphas (A>0; invalid
            // shr slots are bound_ctrl zeros; junk shl slots masked by Ms)
            {
                const float g1 = dmov<0x111>(A), g2 = dmov<0x112>(A),
                            g3 = dmov<0x113>(A), g4 = dmov<0x114>(A),
                            g5 = dmov<0x115>(A), g6 = dmov<0x116>(A),
                            g7 = dmov<0x117>(A), g8 = dmov<0x118>(A);
                const float h1 = dmov<0x101>(A), h2 = dmov<0x102>(A),
                            h3 = dmov<0x103>(A), h4 = dmov<0x104>(A),
                            h5 = dmov<0x105>(A), h6 = dmov<0x106>(A),
                            h7 = dmov<0x107>(A), h8 = dmov<0x108>(A);
                float m = A;
                m = fmaxf(m, fmaxf(fmaxf(g1, g2), fmaxf(g3, g4)));
                m = fmaxf(m, fmaxf(fmaxf(g5, g6), fmaxf(g7, g8)));
                m = fmaxf(m, fmaxf(fmaxf(h1 * Ms[0], h2 * Ms[1]),
                                   fmaxf(h3 * Ms[2], h4 * Ms[3])));
                m = fmaxf(m, fmaxf(fmaxf(h5 * Ms[4], h6 * Ms[5]),
                                   fmaxf(h7 * Ms[6], h8 * Ms[7])));
                const int ex = (int)((__float_as_uint(m) >> 23) & 0xFFu) - 126;
                const float sc = __uint_as_float((uint32_t)(127 - ex) << 23);
                A *= sc;
                lc += ex;
            }
        }
        // final sum of the 9 alphas from lane 0's perspective
        {
            const float h1 = dmov<0x101>(A), h2 = dmov<0x102>(A),
                        h3 = dmov<0x103>(A), h4 = dmov<0x104>(A),
                        h5 = dmov<0x105>(A), h6 = dmov<0x106>(A),
                        h7 = dmov<0x107>(A), h8 = dmov<0x108>(A);
            float u = A;
            u = fmaf(h1, Ms[0], u); u = fmaf(h2, Ms[1], u);
            u = fmaf(h3, Ms[2], u); u = fmaf(h4, Ms[3], u);
            u = fmaf(h5, Ms[4], u); u = fmaf(h6, Ms[5], u);
            u = fmaf(h7, Ms[6], u); u = fmaf(h8, Ms[7], u);
            const float logZ = logf(u) +
                ((float)lc + 3.0f * (float)(sl - 1)) * 0.6931471805599453f;
            if (lane == 0) stats[b * 8 + 1] = logZ;
        }
    } else if (wv == 1) {
        // ---- viterbi value scan, DPP gather (bit-identical values) ----
        const float To = trans_lds[j * NL + j];
        float Ts[8], Us[8];
#pragma unroll
        for (int k = 1; k <= 8; ++k) {
            Ts[k - 1] = (j >= k)     ? trans_lds[(j - k) * NL + j] : -1e30f;
            Us[k - 1] = (j + k <= 8) ? trans_lds[(j + k) * NL + j] : -1e30f;
        }
        float v = lg_lds[j];
        if (lane < NL) val_lds[j] = v;
        for (int tb = 1; tb < BT + 8; tb += 8) {
            float lv[8];
#pragma unroll
            for (int s = 0; s < 8; ++s) lv[s] = lg_lds[(tb + s) * NL + j];
#pragma unroll
            for (int s = 0; s < 8; ++s) {
                const int t = tb + s;
                const float g1 = dmov<0x111>(v), g2 = dmov<0x112>(v),
                            g3 = dmov<0x113>(v), g4 = dmov<0x114>(v),
                            g5 = dmov<0x115>(v), g6 = dmov<0x116>(v),
                            g7 = dmov<0x117>(v), g8 = dmov<0x118>(v);
                const float h1 = dmov<0x101>(v), h2 = dmov<0x102>(v),
                            h3 = dmov<0x103>(v), h4 = dmov<0x104>(v),
                            h5 = dmov<0x105>(v), h6 = dmov<0x106>(v),
                            h7 = dmov<0x107>(v), h8 = dmov<0x108>(v);
                const float c0 = v + To;
                const float c1 = g1 + Ts[0], c2 = g2 + Ts[1], c3 = g3 + Ts[2],
                            c4 = g4 + Ts[3], c5 = g5 + Ts[4], c6 = g6 + Ts[5],
                            c7 = g7 + Ts[6], c8 = g8 + Ts[7];
                const float d1 = h1 + Us[0], d2 = h2 + Us[1], d3 = h3 + Us[2],
                            d4 = h4 + Us[3], d5 = h5 + Us[4], d6 = h6 + Us[5],
                            d7 = h7 + Us[6], d8 = h8 + Us[7];
                // max over the 9 valid candidates (invalid = -1e30); triples
                const float m = fmaxf(
                    fmaxf(fmaxf(fmaxf(c0, c1), c2), fmaxf(fmaxf(c3, c4), c5)),
                    fmaxf(fmaxf(fmaxf(c6, c7), c8), fmaxf(
                        fmaxf(fmaxf(d1, d2), fmaxf(d3, d4)),
                        fmaxf(fmaxf(d5, d6), fmaxf(d7, d8)))));
                const float nv = m + lv[s];
                v = (t < sl) ? nv : v;
                if (lane < NL && t < BT) val_lds[t * NL + lane] = v;
            }
        }
        // last tag = first-argmax(alphaT)  (one-time, keep exact readlanes)
        const float r0 = rlane(v, 0), r1 = rlane(v, 1), r2 = rlane(v, 2),
                    r3 = rlane(v, 3), r4 = rlane(v, 4), r5 = rlane(v, 5),
                    r6 = rlane(v, 6), r7 = rlane(v, 7), r8 = rlane(v, 8);
        const float m = fmaxf(fmaxf(fmaxf(fmaxf(r0, r1), r2),
                                    fmaxf(fmaxf(r3, r4), r5)),
                              fmaxf(fmaxf(r6, r7), r8));
        const int last = (r0 == m) ? 0 : (r1 == m) ? 1 : (r2 == m) ? 2 :
                         (r3 == m) ? 3 : (r4 == m) ? 4 : (r5 == m) ? 5 :
                         (r6 == m) ? 6 : (r7 == m) ? 7 : 8;
        if (lane == 0) vit_lds[BT - 1] = (uint8_t)last;
    } else if (wv == 2) {
        // ---- gold-path score ----
        float s = 0.f;
        for (int t = lane; t < BT; t += 64) {
            const int lb = lab[t];
            if (t < sl) {
                s += lg_lds[t * NL + lb];
                if (t >= 1) s += trans_lds[lab[t - 1] * NL + lb];
            }
        }
#pragma unroll
        for (int off = 32; off >= 1; off >>= 1) s += __shfl_xor(s, off, 64);
        if (lane == 0) stats[b * 8 + 0] = s;
    }
    __syncthreads();

    // ---- fused bp-recompute + nibble-pack (bit-exact first-max) ----
    for (int tm1 = tid; tm1 < BT - 1; tm1 += 256) {
        const int t = tm1 + 1;
        uint64_t p;
        if (t >= sl) {
            p = 0x876543210ull;               // identity nibbles
        } else {
            float vv[NL];
#pragma unroll
            for (int i = 0; i < NL; ++i) vv[i] = val_lds[tm1 * NL + i];
            p = 0;
#pragma unroll
            for (int jj = 0; jj < NL; ++jj) {
                float best = vv[0] + trans_lds[jj];
                int bi = 0;
#pragma unroll
                for (int i = 1; i < NL; ++i) {
                    const float c = vv[i] + trans_lds[i * NL + jj];
                    if (c > best) { best = c; bi = i; }
                }
                p |= (uint64_t)bi << (4 * jj);
            }
        }
        packed_lds[tm1] = p;
    }
    __syncthreads();

    // ---- serial backtrack; unroll x8 batches the address-independent loads
    if (tid == 0) {
        int tag = vit_lds[BT - 1];
#pragma unroll 8
        for (int t = BT - 2; t >= 0; --t) {
            const uint64_t row = packed_lds[t];
            tag = (int)((row >> (4 * tag)) & 15u);
            vit_lds[t] = (uint8_t)tag;
        }
    }
    __syncthreads();

    // ---- stats + vit output ----
    float accv = 0.f, tpv = 0.f, tnv = 0.f, fpv = 0.f;
    for (int t = tid; t < BT; t += 256) {
        const int tg = vit_lds[t];
        const int lb = lab[t];
        const bool msk = t < sl;
        vit_out[(size_t)b * BT + t] = (float)tg;
        if (msk && tg == lb) accv += 1.f;
        if (lb > 0 && tg == lb) tpv += 1.f;
        if (lb > 0 && tg != lb) tnv += 1.f;
        if (msk && lb == 0 && tg > 0) fpv += 1.f;
    }
#pragma unroll
    for (int off = 32; off >= 1; off >>= 1) {
        accv += __shfl_xor(accv, off, 64);
        tpv  += __shfl_xor(tpv,  off, 64);
        tnv  += __shfl_xor(tnv,  off, 64);
        fpv  += __shfl_xor(fpv,  off, 64);
    }
    if (lane == 0) { xw[0][wv] = accv; xw[1][wv] = tpv; xw[2][wv] = tnv; xw[3][wv] = fpv; }
    __syncthreads();
    if (tid == 0) {
        stats[b * 8 + 2] = xw[0][0] + xw[0][1] + xw[0][2] + xw[0][3];
        stats[b * 8 + 3] = xw[1][0] + xw[1][1] + xw[1][2] + xw[1][3];
        stats[b * 8 + 4] = xw[2][0] + xw[2][1] + xw[2][2] + xw[2][3];
        stats[b * 8 + 5] = xw[3][0] + xw[3][1] + xw[3][2] + xw[3][3];
    }
}

// ---------------------------------------------------------------------------
// Kernel 3: reduce the 64 per-batch partials -> tp, tn, fp, loss, accuracy
// ---------------------------------------------------------------------------
__global__ __launch_bounds__(64) void finalize_kernel(
    const float* __restrict__ stats, const int* __restrict__ seqlen,
    float* __restrict__ out)
{
    const int lane = threadIdx.x;
    float score = stats[lane * 8 + 0];
    float logZ  = stats[lane * 8 + 1];
    float accv  = stats[lane * 8 + 2];
    float tpv   = stats[lane * 8 + 3];
    float tnv   = stats[lane * 8 + 4];
    float fpv   = stats[lane * 8 + 5];
    float nll   = logZ - score;
    float slf   = (float)seqlen[lane];
#pragma unroll
    for (int off = 32; off >= 1; off >>= 1) {
        nll  += __shfl_xor(nll,  off, 64);
        accv += __shfl_xor(accv, off, 64);
        tpv  += __shfl_xor(tpv,  off, 64);
        tnv  += __shfl_xor(tnv,  off, 64);
        fpv  += __shfl_xor(fpv,  off, 64);
        slf  += __shfl_xor(slf,  off, 64);
    }
    if (lane == 0) {
        out[NB * BT + 0] = tpv;
        out[NB * BT + 1] = tnv;
        out[NB * BT + 2] = fpv;
        out[NB * BT + 3] = nll / (float)NB;
        out[NB * BT + 4] = accv / slf;
    }
}

extern "C" void kernel_launch(void* const* d_in, const int* in_sizes, int n_in,
                              void* d_out, int out_size, void* d_ws, size_t ws_size,
                              hipStream_t stream)
{
    const float* x      = (const float*)d_in[0];
    const float* W      = (const float*)d_in[1];
    const float* bias   = (const float*)d_in[2];
    const float* trans  = (const float*)d_in[3];
    const int*   label  = (const int*)d_in[4];
    const int*   seqlen = (const int*)d_in[5];
    // d_in[6] = mask: recomputed from seqlen, unused

    float* out    = (float*)d_out;
    float* logits = (float*)d_ws;                  // 64*512*9 floats
    float* stats  = logits + (size_t)NB * BT * NL; // 64*8 floats

    gemm_kernel<<<512, 256, 0, stream>>>(x, W, bias, logits);
    crf_kernel<<<NB, 256, 0, stream>>>(logits, trans, label, seqlen, out, stats);
    finalize_kernel<<<1, 64, 0, stream>>>(stats, seqlen, out);
}

// Round 10
// 214.610 us; speedup vs baseline: 1.2764x; 1.0281x over previous
//
#include <hip/hip_runtime.h>
#include <stdint.h>
#include <math.h>

#define NB 64      // batch
#define BT 512     // time steps
#define NH 768     // hidden
#define NL 9       // labels
#define PBT 528    // padded time rows in crf LDS
#define PADW 772   // padded W row stride (floats)

__device__ __forceinline__ float rlane(float v, int i) {
    return __int_as_float(__builtin_amdgcn_readlane(__float_as_int(v), i));
}

// DPP cross-lane add (gemm reduction): VALU, not DS pipe.
template<int CTRL, int RM>
__device__ __forceinline__ float dppadd(float v) {
    const int t = __builtin_amdgcn_update_dpp(0, __float_as_int(v), CTRL, RM, 0xf, true);
    return v + __int_as_float(t);
}
__device__ __forceinline__ float wave_sum_dpp(float v) {
    v = dppadd<0x111, 0xf>(v);
    v = dppadd<0x112, 0xf>(v);
    v = dppadd<0x114, 0xf>(v);
    v = dppadd<0x118, 0xf>(v);
    v = dppadd<0x142, 0xa>(v);
    v = dppadd<0x143, 0xc>(v);
    return rlane(v, 63);
}

// ---------------------------------------------------------------------------
// Kernel 1: logits = x @ W + b.  (Round-0 verbatim — best verified config.)
// ---------------------------------------------------------------------------
__global__ __launch_bounds__(256, 2) void gemm_kernel(
    const float* __restrict__ x, const float* __restrict__ W,
    const float* __restrict__ bias, float* __restrict__ logits)
{
    __shared__ float wT[NL * PADW];

    const int tid  = threadIdx.x;
    const int lane = tid & 63;

    for (int i = tid; i < NH * NL; i += 256) {
        const int h = i / NL, l = i - h * NL;
        wT[l * PADW + h] = W[i];
    }
    __syncthreads();

    float wr[3][NL][4];
#pragma unroll
    for (int k = 0; k < 3; ++k)
#pragma unroll
        for (int l = 0; l < NL; ++l) {
            const float4 w4 = *(const float4*)&wT[l * PADW + k * 256 + lane * 4];
            wr[k][l][0] = w4.x; wr[k][l][1] = w4.y;
            wr[k][l][2] = w4.z; wr[k][l][3] = w4.w;
        }
    const float bj = bias[lane < NL ? lane : 0];

    const int gwave = (blockIdx.x * blockDim.x + tid) >> 6;
    const int nw    = (gridDim.x * blockDim.x) >> 6;
    const int nrows = NB * BT;
    int row = gwave;
    if (row >= nrows) return;

    const float4* xr = (const float4*)(x + (size_t)row * NH);
    float4 a0 = xr[lane], a1 = xr[64 + lane], a2 = xr[128 + lane];

    while (true) {
        const int nrow = row + nw;
        float4 b0, b1, b2;
        if (nrow < nrows) {   // prefetch next row while computing this one
            const float4* xn = (const float4*)(x + (size_t)nrow * NH);
            b0 = xn[lane]; b1 = xn[64 + lane]; b2 = xn[128 + lane];
        }

        float acc[NL];
#pragma unroll
        for (int l = 0; l < NL; ++l) {
            float s = a0.x * wr[0][l][0];
            s = fmaf(a0.y, wr[0][l][1], s);
            s = fmaf(a0.z, wr[0][l][2], s);
            s = fmaf(a0.w, wr[0][l][3], s);
            s = fmaf(a1.x, wr[1][l][0], s);
            s = fmaf(a1.y, wr[1][l][1], s);
            s = fmaf(a1.z, wr[1][l][2], s);
            s = fmaf(a1.w, wr[1][l][3], s);
            s = fmaf(a2.x, wr[2][l][0], s);
            s = fmaf(a2.y, wr[2][l][1], s);
            s = fmaf(a2.z, wr[2][l][2], s);
            s = fmaf(a2.w, wr[2][l][3], s);
            acc[l] = s;
        }
        float sum[NL];
#pragma unroll
        for (int l = 0; l < NL; ++l) sum[l] = wave_sum_dpp(acc[l]);
        float outv = sum[0];
#pragma unroll
        for (int l = 1; l < NL; ++l) outv = (lane == l) ? sum[l] : outv;
        if (lane < NL) logits[(size_t)row * NL + lane] = outv + bj;

        row = nrow;
        if (row >= nrows) break;
        a0 = b0; a1 = b1; a2 = b2;
    }
}

// ---------------------------------------------------------------------------
// Kernel 2: per-batch CRF.  Block = 256 (4 waves).
// Scans: Round-0 readlane form VERBATIM (the A/B catalog — TLP stack R4,
// 2-chain ILP R7, bpermute R8, DPP R9, register backtrack R6 — all lost to
// it; it is at the chain-latency floor).  Retained from R9: fused
// bp-recompute + nibble-pack (one barrier + bp_lds removed) and unroll-8
// serial backtrack (batches the address-independent ds_read_b64s).
// ---------------------------------------------------------------------------
__global__ __launch_bounds__(256) void crf_kernel(
    const float* __restrict__ logits, const float* __restrict__ trans,
    const int* __restrict__ label, const int* __restrict__ seqlen,
    float* __restrict__ vit_out, float* __restrict__ stats)
{
    __shared__ __align__(16) float lg_lds[PBT * NL];   // padded, zeros past BT
    __shared__ float    val_lds[BT * NL];              // viterbi alpha vectors
    __shared__ float    trans_lds[NL * NL];
    __shared__ uint64_t packed_lds[BT - 1];
    __shared__ uint8_t  vit_lds[BT];
    __shared__ float    xw[4][4];

    const int b    = blockIdx.x;
    const int tid  = threadIdx.x;
    const int lane = tid & 63;
    const int wv   = tid >> 6;
    const int sl   = seqlen[b];
    const float* lg  = logits + (size_t)b * BT * NL;
    const int*   lab = label + (size_t)b * BT;

    // stage logits (float4) + zero padding + transitions
    {
        const float4* src = (const float4*)lg;
        float4* dst = (float4*)lg_lds;
        for (int idx = tid; idx < BT * NL / 4; idx += 256) dst[idx] = src[idx];
        for (int idx = BT * NL + tid; idx < PBT * NL; idx += 256) lg_lds[idx] = 0.f;
        if (tid < NL * NL) trans_lds[tid] = trans[tid];
    }
    __syncthreads();

    if (wv == 0) {
        // ---- logZ scan, scaled-exp domain (Round-0 verbatim) ----
        const int j = lane < NL ? lane : 0;
        float E[NL];
#pragma unroll
        for (int i = 0; i < NL; ++i) E[i] = __expf(trans_lds[i * NL + j]) * 0.125f;
        float A = __expf(lg_lds[j]);
        int lc = 0;
        for (int tb = 1; tb < BT + 8; tb += 8) {
            float P[8];
#pragma unroll
            for (int s = 0; s < 8; ++s) P[s] = __expf(lg_lds[(tb + s) * NL + j]);
#pragma unroll
            for (int s = 0; s < 8; ++s) {
                const int t = tb + s;
                const float r0 = rlane(A, 0), r1 = rlane(A, 1), r2 = rlane(A, 2),
                            r3 = rlane(A, 3), r4 = rlane(A, 4), r5 = rlane(A, 5),
                            r6 = rlane(A, 6), r7 = rlane(A, 7), r8 = rlane(A, 8);
                float p0 = r0 * E[0]; p0 = fmaf(r1, E[1], p0); p0 = fmaf(r2, E[2], p0);
                float p1 = r3 * E[3]; p1 = fmaf(r4, E[4], p1); p1 = fmaf(r5, E[5], p1);
                float p2 = r6 * E[6]; p2 = fmaf(r7, E[7], p2); p2 = fmaf(r8, E[8], p2);
                const float An = ((p0 + p1) + p2) * P[s];
                A = (t < sl) ? An : A;
            }
            // exact pow2 renorm: m is positive & normal here.
            const float m = fmaxf(fmaxf(
                fmaxf(fmaxf(rlane(A, 0), rlane(A, 1)), fmaxf(rlane(A, 2), rlane(A, 3))),
                fmaxf(fmaxf(rlane(A, 4), rlane(A, 5)), fmaxf(rlane(A, 6), rlane(A, 7)))),
                rlane(A, 8));
            const int ex = (int)((__float_as_uint(m) >> 23) & 0xFFu) - 126; // frexp exp
            const float sc = __uint_as_float((uint32_t)(127 - ex) << 23);   // 2^-ex
            A *= sc;
            lc += ex;
        }
        const float sum = ((rlane(A, 0) + rlane(A, 1)) + (rlane(A, 2) + rlane(A, 3))) +
                          ((rlane(A, 4) + rlane(A, 5)) + (rlane(A, 6) + rlane(A, 7))) +
                          rlane(A, 8);
        const float logZ = logf(sum) +
            ((float)lc + 3.0f * (float)(sl - 1)) * 0.6931471805599453f;
        if (lane == 0) stats[b * 8 + 1] = logZ;
    } else if (wv == 1) {
        // ---- viterbi value scan (Round-0 verbatim) ----
        const int j = lane < NL ? lane : 0;
        float tc[NL];
#pragma unroll
        for (int i = 0; i < NL; ++i) tc[i] = trans_lds[i * NL + j];
        float v = lg_lds[j];
        if (lane < NL) val_lds[j] = v;
        for (int tb = 1; tb < BT + 8; tb += 8) {
            float lv[8];
#pragma unroll
            for (int s = 0; s < 8; ++s) lv[s] = lg_lds[(tb + s) * NL + j];
#pragma unroll
            for (int s = 0; s < 8; ++s) {
                const int t = tb + s;
                const float r0 = rlane(v, 0), r1 = rlane(v, 1), r2 = rlane(v, 2),
                            r3 = rlane(v, 3), r4 = rlane(v, 4), r5 = rlane(v, 5),
                            r6 = rlane(v, 6), r7 = rlane(v, 7), r8 = rlane(v, 8);
                const float c0 = r0 + tc[0], c1 = r1 + tc[1], c2 = r2 + tc[2],
                            c3 = r3 + tc[3], c4 = r4 + tc[4], c5 = r5 + tc[5],
                            c6 = r6 + tc[6], c7 = r7 + tc[7], c8 = r8 + tc[8];
                const float m = fmaxf(fmaxf(fmaxf(fmaxf(c0, c1), c2),
                                            fmaxf(fmaxf(c3, c4), c5)),
                                      fmaxf(fmaxf(c6, c7), c8));
                const float nv = m + lv[s];
                v = (t < sl) ? nv : v;
                if (lane < NL && t < BT) val_lds[t * NL + lane] = v;
            }
        }
        // last tag = first-argmax(alphaT)
        const float r0 = rlane(v, 0), r1 = rlane(v, 1), r2 = rlane(v, 2),
                    r3 = rlane(v, 3), r4 = rlane(v, 4), r5 = rlane(v, 5),
                    r6 = rlane(v, 6), r7 = rlane(v, 7), r8 = rlane(v, 8);
        const float m = fmaxf(fmaxf(fmaxf(fmaxf(r0, r1), r2),
                                    fmaxf(fmaxf(r3, r4), r5)),
                              fmaxf(fmaxf(r6, r7), r8));
        const int last = (r0 == m) ? 0 : (r1 == m) ? 1 : (r2 == m) ? 2 :
                         (r3 == m) ? 3 : (r4 == m) ? 4 : (r5 == m) ? 5 :
                         (r6 == m) ? 6 : (r7 == m) ? 7 : 8;
        if (lane == 0) vit_lds[BT - 1] = (uint8_t)last;
    } else if (wv == 2) {
        // ---- gold-path score ----
        float s = 0.f;
        for (int t = lane; t < BT; t += 64) {
            const int lb = lab[t];
            if (t < sl) {
                s += lg_lds[t * NL + lb];
                if (t >= 1) s += trans_lds[lab[t - 1] * NL + lb];
            }
        }
#pragma unroll
        for (int off = 32; off >= 1; off >>= 1) s += __shfl_xor(s, off, 64);
        if (lane == 0) stats[b * 8 + 0] = s;
    }
    __syncthreads();

    // ---- fused bp-recompute + nibble-pack (bit-exact first-max) ----
    for (int tm1 = tid; tm1 < BT - 1; tm1 += 256) {
        const int t = tm1 + 1;
        uint64_t p;
        if (t >= sl) {
            p = 0x876543210ull;               // identity nibbles
        } else {
            float vv[NL];
#pragma unroll
            for (int i = 0; i < NL; ++i) vv[i] = val_lds[tm1 * NL + i];
            p = 0;
#pragma unroll
            for (int jj = 0; jj < NL; ++jj) {
                float best = vv[0] + trans_lds[jj];
                int bi = 0;
#pragma unroll
                for (int i = 1; i < NL; ++i) {
                    const float c = vv[i] + trans_lds[i * NL + jj];
                    if (c > best) { best = c; bi = i; }
                }
                p |= (uint64_t)bi << (4 * jj);
            }
        }
        packed_lds[tm1] = p;
    }
    __syncthreads();

    // ---- serial backtrack; unroll x8 batches the address-independent loads
    if (tid == 0) {
        int tag = vit_lds[BT - 1];
#pragma unroll 8
        for (int t = BT - 2; t >= 0; --t) {
            const uint64_t row = packed_lds[t];
            tag = (int)((row >> (4 * tag)) & 15u);
            vit_lds[t] = (uint8_t)tag;
        }
    }
    __syncthreads();

    // ---- stats + vit output ----
    float accv = 0.f, tpv = 0.f, tnv = 0.f, fpv = 0.f;
    for (int t = tid; t < BT; t += 256) {
        const int tg = vit_lds[t];
        const int lb = lab[t];
        const bool msk = t < sl;
        vit_out[(size_t)b * BT + t] = (float)tg;
        if (msk && tg == lb) accv += 1.f;
        if (lb > 0 && tg == lb) tpv += 1.f;
        if (lb > 0 && tg != lb) tnv += 1.f;
        if (msk && lb == 0 && tg > 0) fpv += 1.f;
    }
#pragma unroll
    for (int off = 32; off >= 1; off >>= 1) {
        accv += __shfl_xor(accv, off, 64);
        tpv  += __shfl_xor(tpv,  off, 64);
        tnv  += __shfl_xor(tnv,  off, 64);
        fpv  += __shfl_xor(fpv,  off, 64);
    }
    if (lane == 0) { xw[0][wv] = accv; xw[1][wv] = tpv; xw[2][wv] = tnv; xw[3][wv] = fpv; }
    __syncthreads();
    if (tid == 0) {
        stats[b * 8 + 2] = xw[0][0] + xw[0][1] + xw[0][2] + xw[0][3];
        stats[b * 8 + 3] = xw[1][0] + xw[1][1] + xw[1][2] + xw[1][3];
        stats[b * 8 + 4] = xw[2][0] + xw[2][1] + xw[2][2] + xw[2][3];
        stats[b * 8 + 5] = xw[3][0] + xw[3][1] + xw[3][2] + xw[3][3];
    }
}

// ---------------------------------------------------------------------------
// Kernel 3: reduce the 64 per-batch partials -> tp, tn, fp, loss, accuracy
// ---------------------------------------------------------------------------
__global__ __launch_bounds__(64) void finalize_kernel(
    const float* __restrict__ stats, const int* __restrict__ seqlen,
    float* __restrict__ out)
{
    const int lane = threadIdx.x;
    float score = stats[lane * 8 + 0];
    float logZ  = stats[lane * 8 + 1];
    float accv  = stats[lane * 8 + 2];
    float tpv   = stats[lane * 8 + 3];
    float tnv   = stats[lane * 8 + 4];
    float fpv   = stats[lane * 8 + 5];
    float nll   = logZ - score;
    float slf   = (float)seqlen[lane];
#pragma unroll
    for (int off = 32; off >= 1; off >>= 1) {
        nll  += __shfl_xor(nll,  off, 64);
        accv += __shfl_xor(accv, off, 64);
        tpv  += __shfl_xor(tpv,  off, 64);
        tnv  += __shfl_xor(tnv,  off, 64);
        fpv  += __shfl_xor(fpv,  off, 64);
        slf  += __shfl_xor(slf,  off, 64);
    }
    if (lane == 0) {
        out[NB * BT + 0] = tpv;
        out[NB * BT + 1] = tnv;
        out[NB * BT + 2] = fpv;
        out[NB * BT + 3] = nll / (float)NB;
        out[NB * BT + 4] = accv / slf;
    }
}

extern "C" void kernel_launch(void* const* d_in, const int* in_sizes, int n_in,
                              void* d_out, int out_size, void* d_ws, size_t ws_size,
                              hipStream_t stream)
{
    const float* x      = (const float*)d_in[0];
    const float* W      = (const float*)d_in[1];
    const float* bias   = (const float*)d_in[2];
    const float* trans  = (const float*)d_in[3];
    const int*   label  = (const int*)d_in[4];
    const int*   seqlen = (const int*)d_in[5];
    // d_in[6] = mask: recomputed from seqlen, unused

    float* out    = (float*)d_out;
    float* logits = (float*)d_ws;                  // 64*512*9 floats
    float* stats  = logits + (size_t)NB * BT * NL; // 64*8 floats

    gemm_kernel<<<512, 256, 0, stream>>>(x, W, bias, logits);
    crf_kernel<<<NB, 256, 0, stream>>>(logits, trans, label, seqlen, out, stats);
    finalize_kernel<<<1, 64, 0, stream>>>(stats, seqlen, out);
}